// Round 4
// baseline (339.863 us; speedup 1.0000x reference)
//
#include <hip/hip_runtime.h>
#include <math.h>

#define N_    200
#define B_    512
#define K1_   100
#define K2_   50
#define ST    36     // padded sH row stride (floats): 144B, 16B-aligned, banks spread by 4j mod 32
#define NBCAP 128    // neighbor-list capacity per node (deg ~ Bin(199,0.1): max ~40; 128 = impossible to exceed)

// out layout: logp [512*2] | s1 [512*100] | s2 [512*50]
#define S1_OFF 1024
#define S2_OFF 52224

__device__ __forceinline__ float lrelu(float v) { return v > 0.f ? v : 0.2f * v; }
__device__ __forceinline__ float sigm(float v)  { return 1.f / (1.f + __expf(-v)); }

// LDS overlay map (bytes), total 65968 (2 blocks/CU; occupancy is grid-capped at 2 anyway):
//     0 : sH    28800  h(200xST) A-B; h1 in-place B-C (barrier-guarded);
//                      rows 100..199 = sXK: xk(100xST) C-E, xk2(50xST) F;
//                      rows 0..99: h2a then h2 in-place, E-F.
// 28800 : sBITS  5600  adj>0 bitmask B-D;  sW2 4096 phase E (alias)
// 34400 : sNbr  25600  per-node u8 neighbor list (incl. self, ascending), phase B only
// 60000 : sES     800
// 60800 : sED     800
// 61600 : sKey   1024  scores (C/F); z-buffer (G)
// 62624 : sSel    400
// 63024 : sVal    400
// 63424 : sXV     512  [x1 | x2] pooled features
// 63936 : sRed     32
// 63968 : sMask2 2000  2-hop mask, 100 rows x stride 5 u32

__global__ __launch_bounds__(256) void gnn_fused(
    const float* __restrict__ x, const float* __restrict__ adj,
    const float* __restrict__ W1, const float* __restrict__ a1s,
    const float* __restrict__ a1d, const float* __restrict__ b1,
    const float* __restrict__ W2g, const float* __restrict__ a2s,
    const float* __restrict__ a2d, const float* __restrict__ b2,
    const float* __restrict__ pw1, const float* __restrict__ pw2,
    const float* __restrict__ fc1w, const float* __restrict__ fc1b,
    const float* __restrict__ fc2w, const float* __restrict__ fc2b,
    const float* __restrict__ fc3w, const float* __restrict__ fc3b,
    const float* __restrict__ bn4g, const float* __restrict__ bn4b,
    const float* __restrict__ bn5g, const float* __restrict__ bn5b,
    float* __restrict__ out)
{
  __shared__ __align__(16) char smem[65968];
  float*         sH    = (float*)smem;
  float*         sXK   = sH + 100 * ST;            // rows 100..199 of sH
  unsigned*      sBITS = (unsigned*)(smem + 28800);
  float*         sW2   = (float*)(smem + 28800);   // alias, used after sBITS dead
  unsigned char* sNbr  = (unsigned char*)(smem + 34400);
  float*         sES   = (float*)(smem + 60000);
  float*         sED   = (float*)(smem + 60800);
  float*         sKey  = (float*)(smem + 61600);
  int*           sSel  = (int*)(smem + 62624);
  float*         sVal  = (float*)(smem + 63024);
  float*         sXV   = (float*)(smem + 63424);
  float*         sRed  = (float*)(smem + 63936);
  unsigned*      sMask2= (unsigned*)(smem + 63968);

  const int t = threadIdx.x;
  const int b = blockIdx.x;
  const float* xb = x   + (size_t)b * N_ * N_;
  const float* ab = adj + (size_t)b * N_ * N_;

  // ---------------- Phase A: h = x @ W1 ; es, ed ----------------
  if (t < N_) {
    float acc[32];
    #pragma unroll
    for (int d = 0; d < 32; ++d) acc[d] = 0.f;
    const float* xr = xb + t * N_;
    for (int k = 0; k < N_; k += 4) {
      float4 xv = *(const float4*)(xr + k);
      #pragma unroll
      for (int kk = 0; kk < 4; ++kk) {
        float xs = (&xv.x)[kk];
        const float* wr = W1 + (k + kk) * 32;   // uniform -> scalar loads
        #pragma unroll
        for (int d = 0; d < 32; ++d) acc[d] += xs * wr[d];
      }
    }
    float es = 0.f, ed = 0.f;
    #pragma unroll
    for (int d = 0; d < 32; ++d) { es += acc[d] * a1s[d]; ed += acc[d] * a1d[d]; }
    sES[t] = es; sED[t] = ed;
    #pragma unroll
    for (int d = 0; d < 32; ++d) sH[t * ST + d] = acc[d];
  }
  __syncthreads();

  // esmax over all nodes (safe softmax bound; leaky_relu is monotone)
  {
    float v = (t < N_) ? sES[t] : -3.0e38f;
    #pragma unroll
    for (int off = 1; off < 64; off <<= 1) v = fmaxf(v, __shfl_xor(v, off, 64));
    if ((t & 63) == 0) sRed[t >> 6] = v;
  }
  __syncthreads();
  {
    float esmax = fmaxf(fmaxf(sRed[0], sRed[1]), fmaxf(sRed[2], sRed[3]));

    // -------------- Phase B: scan adj -> bits + neighbor list; sparse aggregate --------------
    float acc[32];
    if (t < N_) {
      const float* arow = ab + (size_t)t * N_;
      unsigned char* nl = sNbr + t * NBCAP;
      int cnt = 0;
      for (int jw = 0; jw < 7; ++jw) {
        int jbase = jw * 32;
        int lim = (jw < 6) ? 32 : 8;
        unsigned mb = 0u;
        for (int j4 = 0; j4 < lim; j4 += 4) {
          float4 av = *(const float4*)(arow + jbase + j4);
          #pragma unroll
          for (int jj = 0; jj < 4; ++jj) {
            int j = jbase + j4 + jj;
            bool conn = (&av.x)[jj] > 0.f;
            if (conn) mb |= 1u << (j4 + jj);
            if (conn || j == t) nl[cnt++] = (unsigned char)j;   // self-loop in order
          }
        }
        sBITS[t * 7 + jw] = mb;
      }
      // sparse masked-softmax aggregate over own neighbor list (~21 entries)
      float ed_i = sED[t];
      float L = lrelu(ed_i + esmax);
      float ssum = 0.f;
      #pragma unroll
      for (int d = 0; d < 32; ++d) acc[d] = 0.f;
      for (int i = 0; i < cnt; ++i) {
        int j = nl[i];
        float w = __expf(lrelu(ed_i + sES[j]) - L);
        ssum += w;
        const float* hr = &sH[j * ST];            // per-lane gather, 16B aligned
        #pragma unroll
        for (int c = 0; c < 8; ++c) {
          float4 hv = *(const float4*)(hr + c * 4);
          acc[c * 4 + 0] += w * hv.x;
          acc[c * 4 + 1] += w * hv.y;
          acc[c * 4 + 2] += w * hv.z;
          acc[c * 4 + 3] += w * hv.w;
        }
      }
      float inv = 1.f / ssum;
      #pragma unroll
      for (int d = 0; d < 32; ++d) acc[d] = acc[d] * inv + b1[d];
    }
    __syncthreads();                 // all reads of h done -> overwrite with h1
    if (t < N_) {
      #pragma unroll
      for (int d = 0; d < 32; ++d) sH[t * ST + d] = acc[d];
    }
  }
  __syncthreads();

  // -------------- Phase C: TopK pool 1 via barrier-free rank-select --------------
  {
    float npw = 0.f;
    #pragma unroll
    for (int d = 0; d < 32; ++d) npw += pw1[d] * pw1[d];
    npw = sqrtf(npw) + 1e-16f;
    float sc = -1.f;
    if (t < N_) {
      float dp = 0.f;
      #pragma unroll
      for (int d = 0; d < 32; ++d) dp += sH[t * ST + d] * pw1[d];
      sc = sigm(dp / npw);
    }
    sKey[t] = sc;
  }
  __syncthreads();
  if (t < N_) {
    float sc = sKey[t];
    int rank = 0;
    for (int j = 0; j < N_; j += 4) {
      #pragma unroll
      for (int jj = 0; jj < 4; ++jj) {
        float o = sKey[j + jj];                       // uniform -> broadcast
        rank += (o > sc || (o == sc && (j + jj) < t)) ? 1 : 0;
      }
    }
    if (rank < K1_) {                                 // stable desc order == lax.top_k
      sSel[rank] = t; sVal[rank] = sc;
      out[S1_OFF + b * K1_ + rank] = sc;
    }
  }
  __syncthreads();
  // xk = h1[sel]*val. Dest (sH rows 100..199) aliases source rows -> reg staging.
  {
    float tmp[13];
    #pragma unroll
    for (int it = 0; it < 13; ++it) {
      int i = t + it * 256;
      if (i < K1_ * 32) tmp[it] = sH[sSel[i >> 5] * ST + (i & 31)] * sVal[i >> 5];
    }
    __syncthreads();
    #pragma unroll
    for (int it = 0; it < 13; ++it) {
      int i = t + it * 256;
      if (i < K1_ * 32) sXK[(i >> 5) * ST + (i & 31)] = tmp[it];
    }
  }
  __syncthreads();
  // x1 = [max, mean] over 100 pooled nodes
  if (t < 32) {
    float m = -3.0e38f, s = 0.f;
    for (int r = 0; r < K1_; ++r) { float v = sXK[r * ST + t]; m = fmaxf(m, v); s += v; }
    sXV[t] = m; sXV[32 + t] = s / 100.f;
  }

  // -------------- Phase D: 2-hop mask (a2 != 0 | eye), boolean bitsets --------------
  if (t < K1_) {
    int gi = sSel[t];
    #pragma unroll
    for (int w = 0; w < 4; ++w) {
      unsigned m = 0;
      const int lim = (w < 3) ? 32 : 4;
      for (int jj = 0; jj < lim; ++jj) {
        int j = w * 32 + jj;
        int gj = sSel[j];
        unsigned bit = (sBITS[gi * 7 + (gj >> 5)] >> (gj & 31)) & 1u;
        if (j == t) bit = 1u;                       // (A+I) self loop
        m |= bit << jj;
      }
      sMask2[t * 5 + w] = m;
    }
  }
  __syncthreads();
  // sBITS reads done -> overwrite with W2 (alias) while propagating the mask
  for (int i = t; i < 1024; i += 256) sW2[i] = W2g[i];
  {
    unsigned pr0 = 0, pr1 = 0, pr2 = 0, pr3 = 0;
    if (t < K1_) {
      #pragma unroll
      for (int kw = 0; kw < 4; ++kw) {
        unsigned mk = sMask2[t * 5 + kw];
        const int lim = (kw < 3) ? 32 : 4;
        for (int kk = 0; kk < lim; ++kk) {
          if ((mk >> kk) & 1u) {
            int k = kw * 32 + kk;
            pr0 |= sMask2[k * 5 + 0]; pr1 |= sMask2[k * 5 + 1];
            pr2 |= sMask2[k * 5 + 2]; pr3 |= sMask2[k * 5 + 3];
          }
        }
      }
    }
    __syncthreads();
    if (t < K1_) {
      sMask2[t * 5 + 0] = pr0; sMask2[t * 5 + 1] = pr1;
      sMask2[t * 5 + 2] = pr2; sMask2[t * 5 + 3] = pr3;
    }
  }
  __syncthreads();

  // -------------- Phase E: GAT2 --------------
  // h2a = xk @ W2 -> sH rows 0..99 (h1 rows 0..99 dead; xk rows 100..199 untouched)
  if (t < K1_) {
    float xk[32];
    #pragma unroll
    for (int c = 0; c < 8; ++c) *(float4*)&xk[c * 4] = *(const float4*)&sXK[t * ST + c * 4];
    float acc[32];
    #pragma unroll
    for (int d = 0; d < 32; ++d) acc[d] = 0.f;
    #pragma unroll
    for (int k = 0; k < 32; ++k) {
      float xv = xk[k];
      const float* wr = &sW2[k * 32];
      #pragma unroll
      for (int d = 0; d < 32; ++d) acc[d] += xv * wr[d];
    }
    float es = 0.f, ed = 0.f;
    #pragma unroll
    for (int d = 0; d < 32; ++d) { es += acc[d] * a2s[d]; ed += acc[d] * a2d[d]; }
    sES[t] = es; sED[t] = ed;
    #pragma unroll
    for (int d = 0; d < 32; ++d) sH[t * ST + d] = acc[d];
  }
  __syncthreads();
  {
    float v = (t < K1_) ? sES[t] : -3.0e38f;
    #pragma unroll
    for (int off = 1; off < 64; off <<= 1) v = fmaxf(v, __shfl_xor(v, off, 64));
    if ((t & 63) == 0) sRed[t >> 6] = v;
  }
  __syncthreads();
  {
    float esm2 = fmaxf(fmaxf(sRed[0], sRed[1]), fmaxf(sRed[2], sRed[3]));
    float acc[32];
    if (t < K1_) {
      float ed_i = sED[t];
      float L = lrelu(ed_i + esm2);
      float ssum = 0.f;
      #pragma unroll
      for (int d = 0; d < 32; ++d) acc[d] = 0.f;
      #pragma unroll
      for (int jw = 0; jw < 4; ++jw) {
        unsigned mw = sMask2[t * 5 + jw];
        const int lim = (jw < 3) ? 32 : 4;
        for (int jj = 0; jj < lim; ++jj) {
          int j = jw * 32 + jj;
          float w = 0.f;
          if ((mw >> jj) & 1u) w = __expf(lrelu(ed_i + sES[j]) - L);
          ssum += w;
          const float* hr = &sH[j * ST];          // uniform -> broadcast
          #pragma unroll
          for (int d = 0; d < 32; ++d) acc[d] += w * hr[d];
        }
      }
      float inv = 1.f / ssum;
      #pragma unroll
      for (int d = 0; d < 32; ++d) acc[d] = acc[d] * inv + b2[d];
    }
    __syncthreads();               // all reads of h2a done -> overwrite with h2
    if (t < K1_) {
      #pragma unroll
      for (int d = 0; d < 32; ++d) sH[t * ST + d] = acc[d];
    }
  }
  __syncthreads();

  // -------------- Phase F: TopK pool 2 via rank-select --------------
  {
    float npw = 0.f;
    #pragma unroll
    for (int d = 0; d < 32; ++d) npw += pw2[d] * pw2[d];
    npw = sqrtf(npw) + 1e-16f;
    if (t < K1_) {
      float dp = 0.f;
      #pragma unroll
      for (int d = 0; d < 32; ++d) dp += sH[t * ST + d] * pw2[d];
      sKey[t] = sigm(dp / npw);
    }
  }
  __syncthreads();
  if (t < K1_) {
    float sc = sKey[t];
    int rank = 0;
    for (int j = 0; j < K1_; j += 4) {
      #pragma unroll
      for (int jj = 0; jj < 4; ++jj) {
        float o = sKey[j + jj];
        rank += (o > sc || (o == sc && (j + jj) < t)) ? 1 : 0;
      }
    }
    if (rank < K2_) {
      sSel[rank] = t; sVal[rank] = sc;
      out[S2_OFF + b * K2_ + rank] = sc;
    }
  }
  __syncthreads();
  {  // xk2: reads h2 (sH rows 0..99), writes sXK rows 0..49 (sH rows 100..149) - disjoint
    int d = t & 31, r0 = t >> 5;
    for (int r = r0; r < K2_; r += 8) sXK[r * ST + d] = sH[sSel[r] * ST + d] * sVal[r];
  }
  __syncthreads();
  if (t < 32) {
    float m = -3.0e38f, s = 0.f;
    for (int r = 0; r < K2_; ++r) { float v = sXK[r * ST + t]; m = fmaxf(m, v); s += v; }
    sXV[64 + t] = m; sXV[96 + t] = s / 50.f;
  }
  __syncthreads();

  // -------------- Phase G: MLP head --------------
  const float RS = 0.99999500003749969f;   // 1/sqrt(1+1e-5)
  if (t < 32) {
    float z = fc1b[t];
    for (int k = 0; k < 128; ++k) z += sXV[k] * fc1w[k * 32 + t];
    z = fmaxf(z, 0.f);
    z = bn4g[t] * z * RS + bn4b[t];
    sKey[t] = z;
  }
  __syncthreads();
  if (t < 8) {
    float z = fc2b[t];
    for (int k = 0; k < 32; ++k) z += sKey[k] * fc2w[k * 8 + t];
    z = fmaxf(z, 0.f);
    z = bn5g[t] * z * RS + bn5b[t];
    sKey[32 + t] = z;
  }
  __syncthreads();
  if (t < 2) {
    float z = fc3b[t];
    for (int k = 0; k < 8; ++k) z += sKey[32 + k] * fc3w[k * 2 + t];
    sKey[40 + t] = z;
  }
  __syncthreads();
  if (t < 2) {
    float z0 = sKey[40], z1 = sKey[41];
    float m = fmaxf(z0, z1);
    float lse = m + logf(__expf(z0 - m) + __expf(z1 - m));
    out[b * 2 + t] = sKey[40 + t] - lse;
  }
}

extern "C" void kernel_launch(void* const* d_in, const int* in_sizes, int n_in,
                              void* d_out, int out_size, void* d_ws, size_t ws_size,
                              hipStream_t stream) {
  (void)in_sizes; (void)n_in; (void)d_ws; (void)ws_size; (void)out_size;
  const float* x    = (const float*)d_in[0];
  const float* adj  = (const float*)d_in[1];
  const float* W1   = (const float*)d_in[2];
  const float* a1s  = (const float*)d_in[3];
  const float* a1d  = (const float*)d_in[4];
  const float* b1   = (const float*)d_in[5];
  const float* W2   = (const float*)d_in[6];
  const float* a2s  = (const float*)d_in[7];
  const float* a2d  = (const float*)d_in[8];
  const float* b2   = (const float*)d_in[9];
  const float* pw1  = (const float*)d_in[10];
  const float* pw2  = (const float*)d_in[11];
  const float* fc1w = (const float*)d_in[12];
  const float* fc1b = (const float*)d_in[13];
  const float* fc2w = (const float*)d_in[14];
  const float* fc2b = (const float*)d_in[15];
  const float* fc3w = (const float*)d_in[16];
  const float* fc3b = (const float*)d_in[17];
  const float* bn4g = (const float*)d_in[18];
  const float* bn4b = (const float*)d_in[19];
  const float* bn5g = (const float*)d_in[20];
  const float* bn5b = (const float*)d_in[21];

  gnn_fused<<<B_, 256, 0, stream>>>(x, adj, W1, a1s, a1d, b1, W2, a2s, a2d, b2,
                                    pw1, pw2, fc1w, fc1b, fc2w, fc2b, fc3w, fc3b,
                                    bn4g, bn4b, bn5g, bn5b, (float*)d_out);
}